// Round 6
// baseline (61470.966 us; speedup 1.0000x reference)
//
#include <hip/hip_runtime.h>
#include <cstdint>

typedef unsigned short u16;
typedef unsigned int   u32;

#define NL 3
#define NC 4
#define NB 16
#define NT 4096
#define MR (NB*NT)   // 65536 rows
#define BCH 4        // batches per IG chunk
#define MCH (BCH*NT) // 16384 rows per chunk

// ---------------- weight prep: Wih scaled by exp(-log_s), fp32 ----------------
__global__ void k_scale_wih_f32(const float* __restrict__ wih, const float* __restrict__ ls,
                                float* __restrict__ dst, int n){
    int i = blockIdx.x * 256 + threadIdx.x;
    if (i >= n) return;
    int lc = i / (192 * 256);          // 0..11 -> (layer*4 + channel)
    float sc = expf(-ls[lc]);
    dst[i] = wih[i] * sc;
}

// ---------------- GEMM fp32: C = act(A @ W^T + bias) -------------------------
// A (M,K) f32 row-major, W (N,K) f32 row-major. BM=BN=64, BK=32, 256 threads,
// 4x4 per-thread tile. Output f32.
__global__ __launch_bounds__(256) void k_gemm_f32(
    const float* __restrict__ A, const float* __restrict__ W,
    const float* __restrict__ bias, float* __restrict__ Cdst,
    int M, int N, int K, int act)
{
    __shared__ float sA[64][33];
    __shared__ float sB[64][33];

    const int tid = threadIdx.x;
    const int bm = blockIdx.x, bn = blockIdx.y;
    const int ty = tid >> 4;
    const int tx = tid & 15;

    float acc[4][4] = {};

    const int lr = tid >> 2;            // staging row 0..63
    const int lc = (tid & 3) * 8;       // staging col 0,8,16,24

    for (int kk = 0; kk < K; kk += 32) {
        const float* ap = A + (size_t)(bm * 64 + lr) * K + kk + lc;
        const float* bp = W + (size_t)(bn * 64 + lr) * K + kk + lc;
        __syncthreads();
        float4 a0 = *(const float4*)(ap);
        float4 a1 = *(const float4*)(ap + 4);
        float4 b0 = *(const float4*)(bp);
        float4 b1 = *(const float4*)(bp + 4);
        *(float4*)&sA[lr][lc]     = a0;
        *(float4*)&sA[lr][lc + 4] = a1;
        *(float4*)&sB[lr][lc]     = b0;
        *(float4*)&sB[lr][lc + 4] = b1;
        __syncthreads();

        #pragma unroll
        for (int k = 0; k < 32; k++) {
            float av[4], bv[4];
            #pragma unroll
            for (int i = 0; i < 4; i++) av[i] = sA[ty * 4 + i][k];
            #pragma unroll
            for (int j = 0; j < 4; j++) bv[j] = sB[tx * 4 + j][k];
            #pragma unroll
            for (int i = 0; i < 4; i++)
                #pragma unroll
                for (int j = 0; j < 4; j++)
                    acc[i][j] = fmaf(av[i], bv[j], acc[i][j]);
        }
    }

    #pragma unroll
    for (int i = 0; i < 4; i++) {
        int row = bm * 64 + ty * 4 + i;
        #pragma unroll
        for (int j = 0; j < 4; j++) {
            int col = bn * 64 + tx * 4 + j;
            float v = acc[i][j] + bias[col];
            if (act) v = tanhf(v);
            Cdst[(size_t)row * N + col] = v;
        }
    }
}

// ---------------- GRU scan, fp32, conservative ------------------------------
// grid (C, BCH) for one batch chunk, ONE wave. Lane j owns hidden unit j.
__global__ __launch_bounds__(64) void k_scan_f32(
    const float* __restrict__ ig,   // (MCH, 768): row lb*NT+t, col c*192+gate*64+j (bias added)
    const float* __restrict__ Whh,  // layer base: (C,192,64)
    const float* __restrict__ bnp,  // (C,64)
    const float* __restrict__ lsp,  // (C)
    const float* __restrict__ h0p,  // (C,B,64) layer base
    float* __restrict__ ynew,       // layer base: (C,B,T,64) f32 (d_out)
    float* __restrict__ xc,         // (MR,256) f32: concat-channel buffer
    int b0)                         // first global batch of this chunk
{
    const int c = blockIdx.x;
    const int lb = blockIdx.y;          // chunk-local batch
    const int b = b0 + lb;              // global batch
    const int j = threadIdx.x;

    __shared__ float wlds[192][65];
    __shared__ float hlds[64];

    #pragma unroll
    for (int r3 = 0; r3 < 3; r3++) {
        int r = r3 * 64 + j;
        for (int k = 0; k < 64; k++)
            wlds[r][k] = Whh[(size_t)(c * 192 + r) * 64 + k];
    }
    hlds[j] = h0p[(c * NB + b) * 64 + j];
    __syncthreads();

    const float rs  = expf(-lsp[c]);     // 1/s
    const float bnj = bnp[c * 64 + j];

    const float* igp = ig + (size_t)(lb * NT) * 768 + c * 192;
    float* yp = ynew + ((size_t)(c * NB + b) * NT) * 64 + j;
    float* xp = xc + (size_t)(b * NT) * 256 + c * 64 + j;

    for (int t = 0; t < NT; t++) {
        const float* igr = igp + (size_t)t * 768;
        float ig_r = igr[j];
        float ig_z = igr[64 + j];
        float ig_n = igr[128 + j];

        float accr = 0.f, accz = 0.f, accn = 0.f;
        #pragma unroll 16
        for (int k = 0; k < 64; k++) {
            float hk = hlds[k];
            accr = fmaf(hk, wlds[j][k],       accr);
            accz = fmaf(hk, wlds[64 + j][k],  accz);
            accn = fmaf(hk, wlds[128 + j][k], accn);
        }
        float h  = hlds[j];
        float r  = 1.0f / (1.0f + expf(-(ig_r + accr)));
        float z  = 1.0f / (1.0f + expf(-(ig_z + accz)));
        float n  = tanhf(ig_n + r * (accn + bnj));
        float hn = n + z * (h - n);
        float y  = h + (hn - h) * rs;        // (hn-h)/s + h

        __syncthreads();
        hlds[j] = y;
        __syncthreads();

        yp[(size_t)t * 64]  = y;
        xp[(size_t)t * 256] = y;
    }
}

// ---------------- launch ----------------
extern "C" void kernel_launch(void* const* d_in, const int* in_sizes, int n_in,
                              void* d_out, int out_size, void* d_ws, size_t ws_size,
                              hipStream_t stream)
{
    const float* in_inputs = (const float*)d_in[0];
    const float* h0    = (const float*)d_in[1];
    const float* encW1 = (const float*)d_in[3];
    const float* encB1 = (const float*)d_in[4];
    const float* encW2 = (const float*)d_in[5];
    const float* encB2 = (const float*)d_in[6];
    const float* gWih  = (const float*)d_in[7];
    const float* gWhh  = (const float*)d_in[8];
    const float* gB    = (const float*)d_in[9];
    const float* gBn   = (const float*)d_in[10];
    const float* logS  = (const float*)d_in[11];
    const float* mW1   = (const float*)d_in[12];
    const float* mB1   = (const float*)d_in[13];
    const float* mW2   = (const float*)d_in[14];
    const float* mB2   = (const float*)d_in[15];

    // OUTPUT IS F32 (reference's output dtype, per harness contract).
    float* out_f  = (float*)d_out;                    // (B,T,256) f32
    float* ynew_f = out_f + (size_t)MR * 256;         // (L,C,B,T,64) f32

    char* ws = (char*)d_ws;
    size_t off = 0;
    auto alloc = [&](size_t bytes) -> void* {
        void* p = ws + off;
        off = (off + bytes + 255) & ~(size_t)255;
        return p;
    };
    // R0 = IG chunk (50.33MB) and, lifetime-disjoint, XB (67.11MB)
    float* XB  = (float*)alloc((size_t)MR * 256 * 4);    // 67.11 MB
    float* IG  = XB;                                      // alias (IG uses first 50.33 MB)
    float* XA  = (float*)alloc((size_t)MR * 256 * 4);    // 67.11 MB
    float* XC  = (float*)alloc((size_t)MR * 256 * 4);    // 67.11 MB
    float* WIHs= (float*)alloc((size_t)NL * NC * 192 * 256 * 4);  // 2.36 MB
    // total ~203.7 MB

    int nWih = NL * NC * 192 * 256;
    k_scale_wih_f32<<<(nWih + 255) / 256, 256, 0, stream>>>(gWih, logS, WIHs, nWih);

    dim3 blk(256);
    // encoder: XB = tanh(inputs @ W1^T + b1); XA = XB @ W2^T + b2
    k_gemm_f32<<<dim3(MR / 64, 256 / 64), blk, 0, stream>>>(in_inputs, encW1, encB1, XB, MR, 256, 128, 1);
    k_gemm_f32<<<dim3(MR / 64, 256 / 64), blk, 0, stream>>>(XB, encW2, encB2, XA, MR, 256, 256, 0);

    for (int l = 0; l < NL; l++) {
        for (int ch = 0; ch < NB / BCH; ch++) {
            // IG chunk: rows [ch*MCH, (ch+1)*MCH) of (MR,256) @ (768,256)^T + gru_b
            k_gemm_f32<<<dim3(MCH / 64, 768 / 64), blk, 0, stream>>>(
                XA + (size_t)ch * MCH * 256, WIHs + (size_t)l * NC * 192 * 256,
                gB + l * 768, IG, MCH, 768, 256, 0);
            k_scan_f32<<<dim3(NC, BCH), dim3(64), 0, stream>>>(
                IG, gWhh + (size_t)l * NC * 192 * 64, gBn + l * NC * 64, logS + l * NC,
                h0 + (size_t)l * NC * NB * 64,
                ynew_f + (size_t)l * NC * NB * NT * 64, XC, ch * BCH);
        }
        // inter-layer MLP (XB aliases IG; IG dead after scans consumed it)
        k_gemm_f32<<<dim3(MR / 64, 256 / 64), blk, 0, stream>>>(
            XC, mW1 + (size_t)l * 256 * 256, mB1 + l * 256, XB, MR, 256, 256, 1);
        k_gemm_f32<<<dim3(MR / 64, 256 / 64), blk, 0, stream>>>(
            XB, mW2 + (size_t)l * 256 * 256, mB2 + l * 256, XA, MR, 256, 256, 0);
    }
    // faithful to source: mlps[-1] applied a second time -> out (f32)
    k_gemm_f32<<<dim3(MR / 64, 256 / 64), blk, 0, stream>>>(
        XA, mW1 + (size_t)2 * 256 * 256, mB1 + 2 * 256, XB, MR, 256, 256, 1);
    k_gemm_f32<<<dim3(MR / 64, 256 / 64), blk, 0, stream>>>(
        XB, mW2 + (size_t)2 * 256 * 256, mB2 + 2 * 256, out_f, MR, 256, 256, 0);
}

// Round 7
// 12776.627 us; speedup vs baseline: 4.8112x; 4.8112x over previous
//
#include <hip/hip_runtime.h>
#include <cstdint>

typedef unsigned short u16;
typedef unsigned int   u32;

#define NL 3
#define NC 4
#define NB 16
#define NT 4096
#define MR (NB*NT)   // 65536 rows

// ---------------- weight prep: Wih scaled by exp(-log_s), fp32 ----------------
__global__ void k_scale_wih_f32(const float* __restrict__ wih, const float* __restrict__ ls,
                                float* __restrict__ dst, int n){
    int i = blockIdx.x * 256 + threadIdx.x;
    if (i >= n) return;
    int lc = i / (192 * 256);          // 0..11 -> (layer*4 + channel)
    float sc = expf(-ls[lc]);
    dst[i] = wih[i] * sc;
}

// ---------------- GEMM fp32: C = act(A @ W^T + bias) -------------------------
// A (M,K) f32 row-major, W (N,K) f32 row-major. BM=BN=64, BK=32, 256 threads,
// 4x4 per-thread tile. Output f32. UNCHANGED from passing round 6.
__global__ __launch_bounds__(256) void k_gemm_f32(
    const float* __restrict__ A, const float* __restrict__ W,
    const float* __restrict__ bias, float* __restrict__ Cdst,
    int M, int N, int K, int act)
{
    __shared__ float sA[64][33];
    __shared__ float sB[64][33];

    const int tid = threadIdx.x;
    const int bm = blockIdx.x, bn = blockIdx.y;
    const int ty = tid >> 4;
    const int tx = tid & 15;

    float acc[4][4] = {};

    const int lr = tid >> 2;            // staging row 0..63
    const int lc = (tid & 3) * 8;       // staging col 0,8,16,24

    for (int kk = 0; kk < K; kk += 32) {
        const float* ap = A + (size_t)(bm * 64 + lr) * K + kk + lc;
        const float* bp = W + (size_t)(bn * 64 + lr) * K + kk + lc;
        __syncthreads();
        float4 a0 = *(const float4*)(ap);
        float4 a1 = *(const float4*)(ap + 4);
        float4 b0 = *(const float4*)(bp);
        float4 b1 = *(const float4*)(bp + 4);
        *(float4*)&sA[lr][lc]     = a0;
        *(float4*)&sA[lr][lc + 4] = a1;
        *(float4*)&sB[lr][lc]     = b0;
        *(float4*)&sB[lr][lc + 4] = b1;
        __syncthreads();

        #pragma unroll
        for (int k = 0; k < 32; k++) {
            float av[4], bv[4];
            #pragma unroll
            for (int i = 0; i < 4; i++) av[i] = sA[ty * 4 + i][k];
            #pragma unroll
            for (int j = 0; j < 4; j++) bv[j] = sB[tx * 4 + j][k];
            #pragma unroll
            for (int i = 0; i < 4; i++)
                #pragma unroll
                for (int j = 0; j < 4; j++)
                    acc[i][j] = fmaf(av[i], bv[j], acc[i][j]);
        }
    }

    #pragma unroll
    for (int i = 0; i < 4; i++) {
        int row = bm * 64 + ty * 4 + i;
        #pragma unroll
        for (int j = 0; j < 4; j++) {
            int col = bn * 64 + tx * 4 + j;
            float v = acc[i][j] + bias[col];
            if (act) v = tanhf(v);
            Cdst[(size_t)row * N + col] = v;
        }
    }
}

// ---------------- GRU scan: 3 waves (gate r/z/n), Whh in VGPRs ---------------
// grid (C, bch). Lane j of wave g owns gate-row g*64+j. h broadcast via
// readlane (literal lane index after unroll). Distance-2 ig prefetch.
// Numerics identical to the validated round-6 scan (same exp/tanh forms).
__device__ __forceinline__ float rl(float v, int k){
    return __uint_as_float((u32)__builtin_amdgcn_readlane((int)__float_as_uint(v), k));
}

__global__ __launch_bounds__(192) void k_scan3(
    const float* __restrict__ ig,   // (bch*NT,768): row lb*NT+t, col c*192+g*64+j (bias added)
    const float* __restrict__ Whh,  // layer base: (C,192,64)
    const float* __restrict__ bnp,  // (C,64)
    const float* __restrict__ lsp,  // (C)
    const float* __restrict__ h0p,  // (C,B,64) layer base
    float* __restrict__ ynew,       // layer base: (C,B,T,64) f32 (d_out)
    float* __restrict__ xc,         // (MR,256) f32: concat-channel buffer
    int b0)
{
    const int c = blockIdx.x;
    const int lb = blockIdx.y;
    const int b = b0 + lb;
    const int tid = threadIdx.x;
    const int g = tid >> 6, j = tid & 63;

    float w[64];
    const float* wr = Whh + (size_t)(c * 192 + g * 64 + j) * 64;
    #pragma unroll
    for (int k = 0; k < 64; k += 4) {
        float4 t4 = *(const float4*)(wr + k);
        w[k] = t4.x; w[k+1] = t4.y; w[k+2] = t4.z; w[k+3] = t4.w;
    }

    float hj = h0p[(c * NB + b) * 64 + j];
    const float rs  = expf(-lsp[c]);     // 1/s
    const float bnj = bnp[c * 64 + j];

    __shared__ float r_lds[64];
    __shared__ float z_lds[64];
    __shared__ float y_lds[64];

    const float* igp = ig + (size_t)(lb * NT) * 768 + c * 192 + g * 64 + j;
    float* yp = ynew + ((size_t)(c * NB + b) * NT) * 64 + j;
    float* xp = xc + (size_t)(b * NT) * 256 + c * 64 + j;

    float p0 = igp[0];
    float p1 = igp[768];
    for (int t = 0; t < NT; t++) {
        float igv = p0;
        p0 = p1;
        p1 = (t + 2 < NT) ? igp[(size_t)(t + 2) * 768] : 0.f;

        // acc = dot(h, Whh[g*64+j][:]) with 4 independent chains
        float a0 = 0.f, a1 = 0.f, a2 = 0.f, a3 = 0.f;
        #pragma unroll
        for (int k = 0; k < 64; k += 4) {
            a0 = fmaf(rl(hj, k),     w[k],     a0);
            a1 = fmaf(rl(hj, k + 1), w[k + 1], a1);
            a2 = fmaf(rl(hj, k + 2), w[k + 2], a2);
            a3 = fmaf(rl(hj, k + 3), w[k + 3], a3);
        }
        float acc = (a0 + a1) + (a2 + a3);

        if (g == 0)      r_lds[j] = 1.0f / (1.0f + expf(-(igv + acc)));
        else if (g == 1) z_lds[j] = 1.0f / (1.0f + expf(-(igv + acc)));
        __syncthreads();

        if (g == 2) {
            float n  = tanhf(igv + r_lds[j] * (acc + bnj));
            float z  = z_lds[j];
            float hn = n + z * (hj - n);
            float y  = hj + (hn - hj) * rs;     // (hn-h)/s + h
            y_lds[j] = y;
            yp[(size_t)t * 64]  = y;
            xp[(size_t)t * 256] = y;
        }
        __syncthreads();
        hj = y_lds[j];
    }
}

// ---------------- launch ----------------
extern "C" void kernel_launch(void* const* d_in, const int* in_sizes, int n_in,
                              void* d_out, int out_size, void* d_ws, size_t ws_size,
                              hipStream_t stream)
{
    const float* in_inputs = (const float*)d_in[0];
    const float* h0    = (const float*)d_in[1];
    const float* encW1 = (const float*)d_in[3];
    const float* encB1 = (const float*)d_in[4];
    const float* encW2 = (const float*)d_in[5];
    const float* encB2 = (const float*)d_in[6];
    const float* gWih  = (const float*)d_in[7];
    const float* gWhh  = (const float*)d_in[8];
    const float* gB    = (const float*)d_in[9];
    const float* gBn   = (const float*)d_in[10];
    const float* logS  = (const float*)d_in[11];
    const float* mW1   = (const float*)d_in[12];
    const float* mB1   = (const float*)d_in[13];
    const float* mW2   = (const float*)d_in[14];
    const float* mB2   = (const float*)d_in[15];

    float* out_f  = (float*)d_out;                    // (B,T,256) f32
    float* ynew_f = out_f + (size_t)MR * 256;         // (L,C,B,T,64) f32

    // ---- adaptive chunking: maximize batches-per-chunk within ws_size ----
    const size_t xa_b  = (size_t)MR * 256 * 4;                 // 67.11 MB
    const size_t xc_b  = xa_b;                                 // 67.11 MB
    const size_t wih_b = (size_t)NL * NC * 192 * 256 * 4;      // 2.36 MB
    int bch = 16;
    for (;;) {
        size_t igb = (size_t)bch * NT * 768 * 4;
        size_t r0  = igb > xa_b ? igb : xa_b;   // XB aliases region 0
        if (r0 + xa_b + xc_b + wih_b + 4096 <= ws_size || bch == 1) break;
        bch >>= 1;
    }
    const int nch = NB / bch;
    const int mch = bch * NT;

    char* ws = (char*)d_ws;
    size_t off = 0;
    auto alloc = [&](size_t bytes) -> void* {
        void* p = ws + off;
        off = (off + bytes + 255) & ~(size_t)255;
        return p;
    };
    size_t igb = (size_t)bch * NT * 768 * 4;
    float* IG  = (float*)alloc(igb > xa_b ? igb : xa_b);  // region 0
    float* XB  = IG;                                       // alias: lifetimes disjoint
    float* XA  = (float*)alloc(xa_b);
    float* XC  = (float*)alloc(xc_b);
    float* WIHs= (float*)alloc(wih_b);

    int nWih = NL * NC * 192 * 256;
    k_scale_wih_f32<<<(nWih + 255) / 256, 256, 0, stream>>>(gWih, logS, WIHs, nWih);

    dim3 blk(256);
    // encoder: XB = tanh(inputs @ W1^T + b1); XA = XB @ W2^T + b2
    k_gemm_f32<<<dim3(MR / 64, 256 / 64), blk, 0, stream>>>(in_inputs, encW1, encB1, XB, MR, 256, 128, 1);
    k_gemm_f32<<<dim3(MR / 64, 256 / 64), blk, 0, stream>>>(XB, encW2, encB2, XA, MR, 256, 256, 0);

    for (int l = 0; l < NL; l++) {
        for (int ch = 0; ch < nch; ch++) {
            k_gemm_f32<<<dim3(mch / 64, 768 / 64), blk, 0, stream>>>(
                XA + (size_t)ch * mch * 256, WIHs + (size_t)l * NC * 192 * 256,
                gB + l * 768, IG, mch, 768, 256, 0);
            k_scan3<<<dim3(NC, bch), dim3(192), 0, stream>>>(
                IG, gWhh + (size_t)l * NC * 192 * 64, gBn + l * NC * 64, logS + l * NC,
                h0 + (size_t)l * NC * NB * 64,
                ynew_f + (size_t)l * NC * NB * NT * 64, XC, ch * bch);
        }
        // inter-layer MLP (XB aliases IG; IG dead after scans consumed it)
        k_gemm_f32<<<dim3(MR / 64, 256 / 64), blk, 0, stream>>>(
            XC, mW1 + (size_t)l * 256 * 256, mB1 + l * 256, XB, MR, 256, 256, 1);
        k_gemm_f32<<<dim3(MR / 64, 256 / 64), blk, 0, stream>>>(
            XB, mW2 + (size_t)l * 256 * 256, mB2 + l * 256, XA, MR, 256, 256, 0);
    }
    // faithful to source: mlps[-1] applied a second time -> out (f32)
    k_gemm_f32<<<dim3(MR / 64, 256 / 64), blk, 0, stream>>>(
        XA, mW1 + (size_t)2 * 256 * 256, mB1 + 2 * 256, XB, MR, 256, 256, 1);
    k_gemm_f32<<<dim3(MR / 64, 256 / 64), blk, 0, stream>>>(
        XB, mW2 + (size_t)2 * 256 * 256, mB2 + 2 * 256, out_f, MR, 256, 256, 0);
}

// Round 8
// 11154.642 us; speedup vs baseline: 5.5108x; 1.1454x over previous
//
#include <hip/hip_runtime.h>
#include <cstdint>

typedef unsigned short u16;
typedef unsigned int   u32;

#define NL 3
#define NC 4
#define NB 16
#define NT 4096
#define MR (NB*NT)   // 65536 rows

// ---------------- weight prep: Wih scaled by exp(-log_s), fp32 ----------------
__global__ void k_scale_wih_f32(const float* __restrict__ wih, const float* __restrict__ ls,
                                float* __restrict__ dst, int n){
    int i = blockIdx.x * 256 + threadIdx.x;
    if (i >= n) return;
    int lc = i / (192 * 256);          // 0..11 -> (layer*4 + channel)
    float sc = expf(-ls[lc]);
    dst[i] = wih[i] * sc;
}

// ---------------- GEMM fp32: C = act(A @ W^T + bias) -------------------------
// UNCHANGED from passing rounds 6/7.
__global__ __launch_bounds__(256) void k_gemm_f32(
    const float* __restrict__ A, const float* __restrict__ W,
    const float* __restrict__ bias, float* __restrict__ Cdst,
    int M, int N, int K, int act)
{
    __shared__ float sA[64][33];
    __shared__ float sB[64][33];

    const int tid = threadIdx.x;
    const int bm = blockIdx.x, bn = blockIdx.y;
    const int ty = tid >> 4;
    const int tx = tid & 15;

    float acc[4][4] = {};

    const int lr = tid >> 2;            // staging row 0..63
    const int lc = (tid & 3) * 8;       // staging col 0,8,16,24

    for (int kk = 0; kk < K; kk += 32) {
        const float* ap = A + (size_t)(bm * 64 + lr) * K + kk + lc;
        const float* bp = W + (size_t)(bn * 64 + lr) * K + kk + lc;
        __syncthreads();
        float4 a0 = *(const float4*)(ap);
        float4 a1 = *(const float4*)(ap + 4);
        float4 b0 = *(const float4*)(bp);
        float4 b1 = *(const float4*)(bp + 4);
        *(float4*)&sA[lr][lc]     = a0;
        *(float4*)&sA[lr][lc + 4] = a1;
        *(float4*)&sB[lr][lc]     = b0;
        *(float4*)&sB[lr][lc + 4] = b1;
        __syncthreads();

        #pragma unroll
        for (int k = 0; k < 32; k++) {
            float av[4], bv[4];
            #pragma unroll
            for (int i = 0; i < 4; i++) av[i] = sA[ty * 4 + i][k];
            #pragma unroll
            for (int j = 0; j < 4; j++) bv[j] = sB[tx * 4 + j][k];
            #pragma unroll
            for (int i = 0; i < 4; i++)
                #pragma unroll
                for (int j = 0; j < 4; j++)
                    acc[i][j] = fmaf(av[i], bv[j], acc[i][j]);
        }
    }

    #pragma unroll
    for (int i = 0; i < 4; i++) {
        int row = bm * 64 + ty * 4 + i;
        #pragma unroll
        for (int j = 0; j < 4; j++) {
            int col = bn * 64 + tx * 4 + j;
            float v = acc[i][j] + bias[col];
            if (act) v = tanhf(v);
            Cdst[(size_t)row * N + col] = v;
        }
    }
}

// ---------------- GRU scan: ONE wave per (c,b), no barriers, no LDS ----------
// Lane j owns hidden unit j and all 3 gate rows (wr/wz/wn in VGPR/AGPR file).
// h broadcast via readlane: valid without sync inside a single wave (lockstep).
__device__ __forceinline__ float rl(float v, int k){
    return __uint_as_float((u32)__builtin_amdgcn_readlane((int)__float_as_uint(v), k));
}
__device__ __forceinline__ float fsig(float x){
    return 1.0f / (1.0f + __expf(-x));
}
__device__ __forceinline__ float ftanh(float x){
    float e = __expf(-2.0f * fabsf(x));
    float t = (1.0f - e) / (1.0f + e);
    return copysignf(t, x);
}

__global__ __launch_bounds__(64, 1) void k_scan1(
    const float* __restrict__ ig,   // (bch*NT,768): row lb*NT+t, col c*192+g*64+j (bias added)
    const float* __restrict__ Whh,  // layer base: (C,192,64)
    const float* __restrict__ bnp,  // (C,64)
    const float* __restrict__ lsp,  // (C)
    const float* __restrict__ h0p,  // (C,B,64) layer base
    float* __restrict__ ynew,       // layer base: (C,B,T,64) f32 (d_out)
    float* __restrict__ xc,         // (MR,256) f32: concat-channel buffer
    int b0)
{
    const int c = blockIdx.x;
    const int lb = blockIdx.y;
    const int b = b0 + lb;
    const int j = threadIdx.x;      // 0..63

    float wr[64], wz[64], wn[64];
    {
        const float* p0 = Whh + (size_t)(c * 192 +       j) * 64;
        const float* p1 = Whh + (size_t)(c * 192 +  64 + j) * 64;
        const float* p2 = Whh + (size_t)(c * 192 + 128 + j) * 64;
        #pragma unroll
        for (int k = 0; k < 64; k += 4) {
            float4 a = *(const float4*)(p0 + k);
            float4 bq= *(const float4*)(p1 + k);
            float4 cq= *(const float4*)(p2 + k);
            wr[k]=a.x; wr[k+1]=a.y; wr[k+2]=a.z; wr[k+3]=a.w;
            wz[k]=bq.x; wz[k+1]=bq.y; wz[k+2]=bq.z; wz[k+3]=bq.w;
            wn[k]=cq.x; wn[k+1]=cq.y; wn[k+2]=cq.z; wn[k+3]=cq.w;
        }
    }

    float hj = h0p[(c * NB + b) * 64 + j];
    const float rs  = expf(-lsp[c]);     // 1/s
    const float bnj = bnp[c * 64 + j];

    const float* igp = ig + (size_t)(lb * NT) * 768 + c * 192;
    float* yp = ynew + ((size_t)(c * NB + b) * NT) * 64 + j;
    float* xp = xc + (size_t)(b * NT) * 256 + c * 64 + j;

    // distance-2 prefetch of the 3 ig streams
    float pr0 = igp[j],              pz0 = igp[64 + j],        pn0 = igp[128 + j];
    float pr1 = igp[768 + j],        pz1 = igp[768 + 64 + j],  pn1 = igp[768 + 128 + j];

    for (int t = 0; t < NT; t++) {
        float igr = pr0, igz = pz0, ign = pn0;
        pr0 = pr1; pz0 = pz1; pn0 = pn1;
        if (t + 2 < NT) {
            const float* nx = igp + (size_t)(t + 2) * 768;
            pr1 = nx[j]; pz1 = nx[64 + j]; pn1 = nx[128 + j];
        }

        // 12 accumulator chains: 3 gates x 4-way split (order as validated r7)
        float ar0=0.f, ar1=0.f, ar2=0.f, ar3=0.f;
        float az0=0.f, az1=0.f, az2=0.f, az3=0.f;
        float an0=0.f, an1=0.f, an2=0.f, an3=0.f;
        #pragma unroll
        for (int k = 0; k < 64; k += 4) {
            float h0v = rl(hj, k);
            ar0 = fmaf(h0v, wr[k],   ar0);
            az0 = fmaf(h0v, wz[k],   az0);
            an0 = fmaf(h0v, wn[k],   an0);
            float h1v = rl(hj, k + 1);
            ar1 = fmaf(h1v, wr[k+1], ar1);
            az1 = fmaf(h1v, wz[k+1], az1);
            an1 = fmaf(h1v, wn[k+1], an1);
            float h2v = rl(hj, k + 2);
            ar2 = fmaf(h2v, wr[k+2], ar2);
            az2 = fmaf(h2v, wz[k+2], az2);
            an2 = fmaf(h2v, wn[k+2], an2);
            float h3v = rl(hj, k + 3);
            ar3 = fmaf(h3v, wr[k+3], ar3);
            az3 = fmaf(h3v, wz[k+3], az3);
            an3 = fmaf(h3v, wn[k+3], an3);
        }
        float accr = (ar0 + ar1) + (ar2 + ar3);
        float accz = (az0 + az1) + (az2 + az3);
        float accn = (an0 + an1) + (an2 + an3);

        float r  = fsig(igr + accr);
        float z  = fsig(igz + accz);
        float n  = ftanh(ign + r * (accn + bnj));
        float hn = n + z * (hj - n);
        float y  = hj + (hn - hj) * rs;     // (hn-h)/s + h

        yp[(size_t)t * 64]  = y;
        xp[(size_t)t * 256] = y;
        hj = y;                              // lockstep: next readlane sees it
    }
}

// ---------------- launch ----------------
extern "C" void kernel_launch(void* const* d_in, const int* in_sizes, int n_in,
                              void* d_out, int out_size, void* d_ws, size_t ws_size,
                              hipStream_t stream)
{
    const float* in_inputs = (const float*)d_in[0];
    const float* h0    = (const float*)d_in[1];
    const float* encW1 = (const float*)d_in[3];
    const float* encB1 = (const float*)d_in[4];
    const float* encW2 = (const float*)d_in[5];
    const float* encB2 = (const float*)d_in[6];
    const float* gWih  = (const float*)d_in[7];
    const float* gWhh  = (const float*)d_in[8];
    const float* gB    = (const float*)d_in[9];
    const float* gBn   = (const float*)d_in[10];
    const float* logS  = (const float*)d_in[11];
    const float* mW1   = (const float*)d_in[12];
    const float* mB1   = (const float*)d_in[13];
    const float* mW2   = (const float*)d_in[14];
    const float* mB2   = (const float*)d_in[15];

    float* out_f  = (float*)d_out;                    // (B,T,256) f32
    float* ynew_f = out_f + (size_t)MR * 256;         // (L,C,B,T,64) f32

    // ---- adaptive chunking: maximize batches-per-chunk within ws_size ----
    const size_t xa_b  = (size_t)MR * 256 * 4;                 // 67.11 MB
    const size_t xc_b  = xa_b;                                 // 67.11 MB
    const size_t wih_b = (size_t)NL * NC * 192 * 256 * 4;      // 2.36 MB
    int bch = 16;
    for (;;) {
        size_t igb = (size_t)bch * NT * 768 * 4;
        size_t r0  = igb > xa_b ? igb : xa_b;   // XB aliases region 0
        if (r0 + xa_b + xc_b + wih_b + 4096 <= ws_size || bch == 1) break;
        bch >>= 1;
    }
    const int nch = NB / bch;
    const int mch = bch * NT;

    char* ws = (char*)d_ws;
    size_t off = 0;
    auto alloc = [&](size_t bytes) -> void* {
        void* p = ws + off;
        off = (off + bytes + 255) & ~(size_t)255;
        return p;
    };
    size_t igb = (size_t)bch * NT * 768 * 4;
    float* IG  = (float*)alloc(igb > xa_b ? igb : xa_b);  // region 0
    float* XB  = IG;                                       // alias: lifetimes disjoint
    float* XA  = (float*)alloc(xa_b);
    float* XC  = (float*)alloc(xc_b);
    float* WIHs= (float*)alloc(wih_b);

    int nWih = NL * NC * 192 * 256;
    k_scale_wih_f32<<<(nWih + 255) / 256, 256, 0, stream>>>(gWih, logS, WIHs, nWih);

    dim3 blk(256);
    // encoder: XB = tanh(inputs @ W1^T + b1); XA = XB @ W2^T + b2
    k_gemm_f32<<<dim3(MR / 64, 256 / 64), blk, 0, stream>>>(in_inputs, encW1, encB1, XB, MR, 256, 128, 1);
    k_gemm_f32<<<dim3(MR / 64, 256 / 64), blk, 0, stream>>>(XB, encW2, encB2, XA, MR, 256, 256, 0);

    for (int l = 0; l < NL; l++) {
        for (int ch = 0; ch < nch; ch++) {
            k_gemm_f32<<<dim3(mch / 64, 768 / 64), blk, 0, stream>>>(
                XA + (size_t)ch * mch * 256, WIHs + (size_t)l * NC * 192 * 256,
                gB + l * 768, IG, mch, 768, 256, 0);
            k_scan1<<<dim3(NC, bch), dim3(64), 0, stream>>>(
                IG, gWhh + (size_t)l * NC * 192 * 64, gBn + l * NC * 64, logS + l * NC,
                h0 + (size_t)l * NC * NB * 64,
                ynew_f + (size_t)l * NC * NB * NT * 64, XC, ch * bch);
        }
        // inter-layer MLP (XB aliases IG; IG dead after scans consumed it)
        k_gemm_f32<<<dim3(MR / 64, 256 / 64), blk, 0, stream>>>(
            XC, mW1 + (size_t)l * 256 * 256, mB1 + l * 256, XB, MR, 256, 256, 1);
        k_gemm_f32<<<dim3(MR / 64, 256 / 64), blk, 0, stream>>>(
            XB, mW2 + (size_t)l * 256 * 256, mB2 + l * 256, XA, MR, 256, 256, 0);
    }
    // faithful to source: mlps[-1] applied a second time -> out (f32)
    k_gemm_f32<<<dim3(MR / 64, 256 / 64), blk, 0, stream>>>(
        XA, mW1 + (size_t)2 * 256 * 256, mB1 + 2 * 256, XB, MR, 256, 256, 1);
    k_gemm_f32<<<dim3(MR / 64, 256 / 64), blk, 0, stream>>>(
        XB, mW2 + (size_t)2 * 256 * 256, mB2 + 2 * 256, out_f, MR, 256, 256, 0);
}